// Round 7
// baseline (259.363 us; speedup 1.0000x reference)
//
#include <hip/hip_runtime.h>

typedef __attribute__((ext_vector_type(4))) float f32x4;
typedef __attribute__((ext_vector_type(8))) _Float16 f16x8;

#define BM 128
#define BK 64

// workspace layout (bytes)
#define OFF_W0T 0                                   // 512*128*2   = 131072
#define OFF_WT  131072                              // 6*512*1536*2 = 9437184
#define OFF_X0  (OFF_WT + 6*512*1536*2)             // 16384*128*2 = 4194304
#define OFF_Y0  (OFF_X0 + 16384*128*2)              // 16*1056*512*2
#define OFF_Y1  (OFF_Y0 + 16*1056*512*2)

__device__ __forceinline__ void load_lds16(const void* g, void* s) {
    __builtin_amdgcn_global_load_lds(
        (const __attribute__((address_space(1))) void*)g,
        (__attribute__((address_space(3))) void*)s, 16, 0, 0);
}

// ---- weight prep: ws [6][3][512][512] (ci-major in, co inner) -> wt [l][co][t*512+ci] f16
//      w0 [128][512] -> w0t [co][ci] f16
__global__ __launch_bounds__(256)
void wprep(const float* __restrict__ ws, const float* __restrict__ w0,
           _Float16* __restrict__ wt, _Float16* __restrict__ w0t)
{
    __shared__ float t[64][65];
    const int tid = threadIdx.x;
    const int tr = tid >> 6;       // 0..3
    const int tc = tid & 63;
    const int z = blockIdx.z;
    if (z < 18) {
        const int l = z / 3, tp = z % 3;
        const float* src = ws + (size_t)z * 512 * 512;      // [ci][co]
        const int ci0 = blockIdx.y * 64, co0 = blockIdx.x * 64;
        #pragma unroll
        for (int i = 0; i < 16; ++i) { int r = i*4 + tr; t[r][tc] = src[(ci0 + r)*512 + co0 + tc]; }
        __syncthreads();
        _Float16* dst = wt + (size_t)l * 512 * 1536;
        #pragma unroll
        for (int i = 0; i < 16; ++i) { int r = i*4 + tr; dst[(co0 + r)*1536 + tp*512 + ci0 + tc] = (_Float16)t[tc][r]; }
    } else {
        if (blockIdx.y >= 2) return;
        const int ci0 = blockIdx.y * 64, co0 = blockIdx.x * 64;
        #pragma unroll
        for (int i = 0; i < 16; ++i) { int r = i*4 + tr; t[r][tc] = w0[(ci0 + r)*512 + co0 + tc]; }
        __syncthreads();
        #pragma unroll
        for (int i = 0; i < 16; ++i) { int r = i*4 + tr; w0t[(co0 + r)*128 + ci0 + tc] = (_Float16)t[tc][r]; }
    }
}

// ---- zero the 16-row pads of both activation buffers (as u32)
__global__ __launch_bounds__(256)
void zeropad(_Float16* __restrict__ Y0, _Float16* __restrict__ Y1)
{
    const int i = blockIdx.x * 256 + threadIdx.x;       // 262144 total
    const unsigned c2   = i & 255;                      // u32 col (512 f16 / row)
    const unsigned t2   = ((unsigned)i) >> 8;
    const unsigned prow = t2 & 31;
    const unsigned b    = (t2 >> 5) & 15;
    const unsigned buf  = t2 >> 9;
    const unsigned row  = prow < 16 ? prow : (1024 + prow); // [0,16) and [1040,1056)
    unsigned* p = (unsigned*)(buf ? Y1 : Y0);
    p[((size_t)b * 1056 + row) * 256 + c2] = 0u;
}

// ---- bilinear sample + concat -> X0 [16384][128] f16
__global__ __launch_bounds__(256)
void sample_kernel(const float* __restrict__ verts, const float* __restrict__ fm,
                   _Float16* __restrict__ X0)
{
    const int p = blockIdx.x * 4 + (threadIdx.x >> 6);  // 0..16383
    const int lane = threadIdx.x & 63;
    const int b = p >> 10;
    const float vy = verts[p*2], vx = verts[p*2 + 1];
    const float cy = (vy + 1.f) * 127.5f;
    const float cx = (vx + 1.f) * 127.5f;
    const float fy = floorf(cy), fx = floorf(cx);
    const int y0 = (int)fy, x0 = (int)fx;
    const float wy = cy - fy, wx = cx - fx;
    float w00 = (1.f - wy) * (1.f - wx), w01 = (1.f - wy) * wx;
    float w10 = wy * (1.f - wx),         w11 = wy * wx;
    const bool vy0 = (unsigned)y0 < 256u, vy1 = (unsigned)(y0 + 1) < 256u;
    const bool vx0 = (unsigned)x0 < 256u, vx1 = (unsigned)(x0 + 1) < 256u;
    w00 = (vy0 && vx0) ? w00 : 0.f;
    w01 = (vy0 && vx1) ? w01 : 0.f;
    w10 = (vy1 && vx0) ? w10 : 0.f;
    w11 = (vy1 && vx1) ? w11 : 0.f;
    const int yc0 = min(max(y0, 0), 255), yc1 = min(max(y0 + 1, 0), 255);
    const int xc0 = min(max(x0, 0), 255), xc1 = min(max(x0 + 1, 0), 255);
    const float* base = fm + (size_t)b * (256 * 256 * 126);
    const float* p00 = base + (yc0 * 256 + xc0) * 126;
    const float* p01 = base + (yc0 * 256 + xc1) * 126;
    const float* p10 = base + (yc1 * 256 + xc0) * 126;
    const float* p11 = base + (yc1 * 256 + xc1) * 126;
    _Float16* xr = X0 + (size_t)p * 128;
    for (int c = lane; c < 126; c += 64) {
        float a = w00 * p00[c] + w01 * p01[c] + w10 * p10[c] + w11 * p11[c];
        xr[c] = (_Float16)a;
    }
    if (lane < 2) xr[126 + lane] = (_Float16)(lane ? vx : vy);
}

// ---- layer-0 GEMM (K=128), m97 structure, 128x128 tile
template<int KTOT>
__global__ __launch_bounds__(256)
void conv_gemm(const _Float16* __restrict__ A, int a_row_stride, int a_batch_stride,
               const _Float16* __restrict__ WT, const float* __restrict__ bias,
               _Float16* __restrict__ Out, int o_row_stride, int o_batch_stride,
               int dil)
{
    __shared__ _Float16 Ald[BM * BK];
    __shared__ _Float16 Bld[BM * BK];
    const int tid  = threadIdx.x;
    const int wid  = tid >> 6;
    const int lane = tid & 63;
    const int b    = blockIdx.x >> 3;
    const int n0   = (blockIdx.x & 7) * BM;
    const int co0  = blockIdx.y * BM;
    const int wm   = wid >> 1, wn = wid & 1;

    const _Float16* Ab = A + (size_t)b * a_batch_stride + (size_t)n0 * a_row_stride;

    f32x4 acc[4][4] = {};

    const int srow = lane >> 3;
    const int scol = (lane & 7) * 8;

    for (int ks = 0; ks < KTOT / BK; ++ks) {
        int ci0, shift;
        if (KTOT == 128) { ci0 = ks * 64; shift = 0; }
        else             { int t = ks >> 3; ci0 = (ks & 7) * 64; shift = (t - 1) * dil; }
        const _Float16* Arow = Ab + (long)shift * a_row_stride + ci0 + scol;
        const _Float16* Brow = WT + (size_t)co0 * KTOT + ks * 64 + scol;
        #pragma unroll
        for (int i = 0; i < 4; ++i) {
            const int r0 = wid * 32 + i * 8;
            load_lds16(Arow + (size_t)(r0 + srow) * a_row_stride, &Ald[r0 * BK]);
            load_lds16(Brow + (size_t)(r0 + srow) * KTOT,         &Bld[r0 * BK]);
        }
        __syncthreads();
        #pragma unroll
        for (int kf = 0; kf < 2; ++kf) {
            f16x8 af[4], bfr[4];
            #pragma unroll
            for (int f = 0; f < 4; ++f) {
                af[f]  = *(const f16x8*)&Ald[(wm*64 + f*16 + (lane & 15)) * BK + kf*32 + (lane >> 4) * 8];
                bfr[f] = *(const f16x8*)&Bld[(wn*64 + f*16 + (lane & 15)) * BK + kf*32 + (lane >> 4) * 8];
            }
            #pragma unroll
            for (int m = 0; m < 4; ++m)
                #pragma unroll
                for (int n = 0; n < 4; ++n)
                    acc[m][n] = __builtin_amdgcn_mfma_f32_16x16x32_f16(af[m], bfr[n], acc[m][n], 0, 0, 0);
        }
        __syncthreads();
    }

    _Float16* Ob = Out + (size_t)b * o_batch_stride + (size_t)n0 * o_row_stride;
    #pragma unroll
    for (int n = 0; n < 4; ++n) {
        const int co = co0 + wn*64 + n*16 + (lane & 15);
        const float bv = bias[co];
        #pragma unroll
        for (int m = 0; m < 4; ++m) {
            #pragma unroll
            for (int j = 0; j < 4; ++j) {
                const int row = wm*64 + m*16 + (lane >> 4)*4 + j;
                float v = acc[m][n][j] + bv;
                v = fmaxf(v, 0.f);
                Ob[(size_t)row * o_row_stride + co] = (_Float16)v;
            }
        }
    }
}

// ---- mid-layer GEMM (r7): 4 waves (256 thr), block 256x128, wave-tile 128x64.
// 3-deep LDS pipeline, 12 gloads/wave/tile, counted vmcnt(12), T2 swizzle.
// ONE barrier per tile; intra-tile: stage -> 24 ds_reads -> 64 MFMA, compiler-
// scheduled lgkmcnt overlap. 1 wave/SIMD -> VGPR budget up to 512.
#define NT8 24
__global__ __launch_bounds__(256, 1)
void conv_gemm8(const _Float16* __restrict__ A, const _Float16* __restrict__ WT,
                const float* __restrict__ bias, _Float16* __restrict__ Out, int dil)
{
    extern __shared__ _Float16 smem[];
    _Float16* Ald = smem;                 // [3][256*64]
    _Float16* Bld = smem + 3 * 256 * 64;  // [3][128*64]

    const int tid  = threadIdx.x;
    const int wid  = tid >> 6;            // 0..3
    const int lane = tid & 63;
    const int wm   = wid >> 1;            // 0..1 : 128-row half
    const int wn   = wid & 1;             // 0..1 : 64-col half

    // XCD-aware bijective swizzle (256 blocks, 256%8==0)
    const int orig = blockIdx.x;
    const int swz  = (orig & 7) * 32 + (orig >> 3);
    const int nblk = swz & 3;             // 4 col-tiles of 128
    const int mblk = swz >> 2;            // 64 row-tiles of 256
    const int b     = mblk >> 2;
    const int n0row = (mblk & 3) * 256;
    const int co0   = nblk * 128;

    const _Float16* Ab = A + (size_t)b * (1056 * 512) + (size_t)n0row * 512;

    // staging: each gload_lds covers 8 rows x 64 k (1KB/wave-instr)
    const int srow = lane >> 3;                              // row within 8-row group
    const int scol = (((lane & 7) ^ (lane >> 3)) << 3);      // pre-swizzled global col (f16)

    f32x4 acc[8][4] = {};

    auto stageA = [&](int kt, int j, int ci0, int shift) {   // j = 0..7; wave covers rows [64*wid, +64)
        const int rb = 64 * wid + 8 * j;
        const _Float16* src = Ab + (long)(rb + srow + shift) * 512 + ci0 + scol;
        load_lds16(src, Ald + (kt % 3) * (256 * 64) + rb * 64);
    };
    auto stageB = [&](int kt, int j, int kk) {               // j = 0..3; wave covers rows [32*wid, +32)
        const int rb = 32 * wid + 8 * j;
        const _Float16* src = WT + (size_t)(co0 + rb + srow) * 1536 + kk + scol;
        load_lds16(src, Bld + (kt % 3) * (128 * 64) + rb * 64);
    };
    auto kinfo = [&](int ks, int& ci0, int& shift) {
        const int t = ks >> 3; ci0 = (ks & 7) * 64; shift = (t - 1) * dil;
    };
    auto stage_tile = [&](int kt) {
        int ci0, sh; kinfo(kt, ci0, sh);
        #pragma unroll
        for (int j = 0; j < 8; ++j) stageA(kt, j, ci0, sh);
        #pragma unroll
        for (int j = 0; j < 4; ++j) stageB(kt, j, kt * 64);
    };

    // prologue: issue tiles 0 and 1 (12 loads each per wave, fixed order)
    stage_tile(0);
    stage_tile(1);

    for (int kt = 0; kt < NT8; ++kt) {
        // counted wait: tile kt landed, tile kt+1 (12 loads/wave) stays in flight
        if (kt < NT8 - 1) asm volatile("s_waitcnt vmcnt(12)" ::: "memory");
        else              asm volatile("s_waitcnt vmcnt(0)" ::: "memory");
        __builtin_amdgcn_s_barrier();

        // issue next-next tile's loads first (earliest possible start)
        if (kt + 2 < NT8) stage_tile(kt + 2);

        const _Float16* Abuf = Ald + (kt % 3) * (256 * 64);
        const _Float16* Bbuf = Bld + (kt % 3) * (128 * 64);

        f16x8 bfr[4][2];
        #pragma unroll
        for (int nf = 0; nf < 4; ++nf) {
            const int row = wn * 64 + nf * 16 + (lane & 15);
            #pragma unroll
            for (int kf = 0; kf < 2; ++kf) {
                const int slot = (kf * 4 + (lane >> 4)) ^ (row & 7);
                bfr[nf][kf] = *(const f16x8*)&Bbuf[row * 64 + slot * 8];
            }
        }
        f16x8 af[8][2];
        #pragma unroll
        for (int mf = 0; mf < 8; ++mf) {
            const int row = wm * 128 + mf * 16 + (lane & 15);
            #pragma unroll
            for (int kf = 0; kf < 2; ++kf) {
                const int slot = (kf * 4 + (lane >> 4)) ^ (row & 7);
                af[mf][kf] = *(const f16x8*)&Abuf[row * 64 + slot * 8];
            }
        }

        #pragma unroll
        for (int mf = 0; mf < 8; ++mf)
            #pragma unroll
            for (int nf = 0; nf < 4; ++nf)
                #pragma unroll
                for (int kf = 0; kf < 2; ++kf)
                    acc[mf][nf] = __builtin_amdgcn_mfma_f32_16x16x32_f16(
                        af[mf][kf], bfr[nf][kf], acc[mf][nf], 0, 0, 0);
    }

    _Float16* Ob = Out + (size_t)b * (1056 * 512) + (size_t)n0row * 512;
    #pragma unroll
    for (int nf = 0; nf < 4; ++nf) {
        const int co = co0 + wn * 64 + nf * 16 + (lane & 15);
        const float bv = bias[co];
        #pragma unroll
        for (int mf = 0; mf < 8; ++mf) {
            #pragma unroll
            for (int j = 0; j < 4; ++j) {
                const int row = wm * 128 + mf * 16 + (lane >> 4) * 4 + j;
                float v = acc[mf][nf][j] + bv;
                v = fmaxf(v, 0.f);
                Ob[(size_t)row * 512 + co] = (_Float16)v;
            }
        }
    }
}

// ---- final 1x1 conv to 2 channels, fp32 out. One wave per row.
__global__ __launch_bounds__(256)
void final_conv(const _Float16* __restrict__ Y, const float* __restrict__ woff,
                float* __restrict__ out)
{
    const int r = blockIdx.x * 4 + (threadIdx.x >> 6);  // 0..16383
    const int lane = threadIdx.x & 63;
    const int b = r >> 10, n = r & 1023;
    const _Float16* yp = Y + ((size_t)b * 1056 + n) * 512 + lane * 8;
    f16x8 yv = *(const f16x8*)yp;
    const int ci0 = lane * 8;
    float s0 = 0.f, s1 = 0.f;
    #pragma unroll
    for (int e = 0; e < 8; ++e) {
        float y = (float)yv[e];
        s0 += y * woff[(ci0 + e) * 2 + 0];
        s1 += y * woff[(ci0 + e) * 2 + 1];
    }
    #pragma unroll
    for (int off = 32; off; off >>= 1) {
        s0 += __shfl_down(s0, off);
        s1 += __shfl_down(s1, off);
    }
    if (lane == 0) { out[r*2] = s0; out[r*2 + 1] = s1; }
}

extern "C" void kernel_launch(void* const* d_in, const int* in_sizes, int n_in,
                              void* d_out, int out_size, void* d_ws, size_t ws_size,
                              hipStream_t stream)
{
    const float* verts = (const float*)d_in[0];
    const float* fm    = (const float*)d_in[1];
    const float* w0    = (const float*)d_in[2];
    const float* b0    = (const float*)d_in[3];
    const float* ws    = (const float*)d_in[4];
    const float* bs    = (const float*)d_in[5];
    const float* woff  = (const float*)d_in[6];
    float* out = (float*)d_out;

    char* wsp = (char*)d_ws;
    _Float16* W0T = (_Float16*)(wsp + OFF_W0T);
    _Float16* WT  = (_Float16*)(wsp + OFF_WT);
    _Float16* X0  = (_Float16*)(wsp + OFF_X0);
    _Float16* Y0  = (_Float16*)(wsp + OFF_Y0);
    _Float16* Y1  = (_Float16*)(wsp + OFF_Y1);
    _Float16* Y0i = Y0 + 16 * 512;   // interior (row 0 of batch 0)
    _Float16* Y1i = Y1 + 16 * 512;

    hipFuncSetAttribute(reinterpret_cast<const void*>(&conv_gemm8),
                        hipFuncAttributeMaxDynamicSharedMemorySize, 147456);

    wprep<<<dim3(8, 8, 19), 256, 0, stream>>>(ws, w0, WT, W0T);
    zeropad<<<1024, 256, 0, stream>>>(Y0, Y1);
    sample_kernel<<<4096, 256, 0, stream>>>(verts, fm, X0);

    // layer 0: 1x1 conv, K=128 (old structure, small K)
    conv_gemm<128><<<dim3(128, 4), 256, 0, stream>>>(
        X0, 128, 1024 * 128, W0T, b0, Y0i, 512, 1056 * 512, 1);

    // 6 dilated mid layers, K=1536, r7 kernel
    const int DIL[6] = {1, 3, 9, 9, 3, 1};
    _Float16* bufs[2] = {Y0i, Y1i};
    for (int l = 0; l < 6; ++l) {
        conv_gemm8<<<256, 256, 147456, stream>>>(
            bufs[l & 1],
            WT + (size_t)l * 512 * 1536, bs + (size_t)l * 512,
            bufs[(l + 1) & 1], DIL[l]);
    }

    // final projection (reads Y0i after 6 layers)
    final_conv<<<4096, 256, 0, stream>>>(bufs[0], woff, out);
}

// Round 8
// 201.711 us; speedup vs baseline: 1.2858x; 1.2858x over previous
//
#include <hip/hip_runtime.h>

typedef __attribute__((ext_vector_type(4))) float f32x4;
typedef __attribute__((ext_vector_type(8))) _Float16 f16x8;

#define BM 128
#define BK 64

// workspace layout (bytes)
#define OFF_W0T 0                                   // 512*128*2   = 131072
#define OFF_WT  131072                              // 6*512*1536*2 = 9437184
#define OFF_X0  (OFF_WT + 6*512*1536*2)             // 16384*128*2 = 4194304
#define OFF_Y0  (OFF_X0 + 16384*128*2)              // 16*1056*512*2
#define OFF_Y1  (OFF_Y0 + 16*1056*512*2)

__device__ __forceinline__ void load_lds16(const void* g, void* s) {
    __builtin_amdgcn_global_load_lds(
        (const __attribute__((address_space(1))) void*)g,
        (__attribute__((address_space(3))) void*)s, 16, 0, 0);
}

// ---- weight prep: ws [6][3][512][512] (ci-major in, co inner) -> wt [l][co][t*512+ci] f16
//      w0 [128][512] -> w0t [co][ci] f16
__global__ __launch_bounds__(256)
void wprep(const float* __restrict__ ws, const float* __restrict__ w0,
           _Float16* __restrict__ wt, _Float16* __restrict__ w0t)
{
    __shared__ float t[64][65];
    const int tid = threadIdx.x;
    const int tr = tid >> 6;       // 0..3
    const int tc = tid & 63;
    const int z = blockIdx.z;
    if (z < 18) {
        const int l = z / 3, tp = z % 3;
        const float* src = ws + (size_t)z * 512 * 512;      // [ci][co]
        const int ci0 = blockIdx.y * 64, co0 = blockIdx.x * 64;
        #pragma unroll
        for (int i = 0; i < 16; ++i) { int r = i*4 + tr; t[r][tc] = src[(ci0 + r)*512 + co0 + tc]; }
        __syncthreads();
        _Float16* dst = wt + (size_t)l * 512 * 1536;
        #pragma unroll
        for (int i = 0; i < 16; ++i) { int r = i*4 + tr; dst[(co0 + r)*1536 + tp*512 + ci0 + tc] = (_Float16)t[tc][r]; }
    } else {
        if (blockIdx.y >= 2) return;
        const int ci0 = blockIdx.y * 64, co0 = blockIdx.x * 64;
        #pragma unroll
        for (int i = 0; i < 16; ++i) { int r = i*4 + tr; t[r][tc] = w0[(ci0 + r)*512 + co0 + tc]; }
        __syncthreads();
        #pragma unroll
        for (int i = 0; i < 16; ++i) { int r = i*4 + tr; w0t[(co0 + r)*128 + ci0 + tc] = (_Float16)t[tc][r]; }
    }
}

// ---- zero the 16-row pads of both activation buffers (as u32)
__global__ __launch_bounds__(256)
void zeropad(_Float16* __restrict__ Y0, _Float16* __restrict__ Y1)
{
    const int i = blockIdx.x * 256 + threadIdx.x;       // 262144 total
    const unsigned c2   = i & 255;                      // u32 col (512 f16 / row)
    const unsigned t2   = ((unsigned)i) >> 8;
    const unsigned prow = t2 & 31;
    const unsigned b    = (t2 >> 5) & 15;
    const unsigned buf  = t2 >> 9;
    const unsigned row  = prow < 16 ? prow : (1024 + prow); // [0,16) and [1040,1056)
    unsigned* p = (unsigned*)(buf ? Y1 : Y0);
    p[((size_t)b * 1056 + row) * 256 + c2] = 0u;
}

// ---- bilinear sample + concat -> X0 [16384][128] f16
__global__ __launch_bounds__(256)
void sample_kernel(const float* __restrict__ verts, const float* __restrict__ fm,
                   _Float16* __restrict__ X0)
{
    const int p = blockIdx.x * 4 + (threadIdx.x >> 6);  // 0..16383
    const int lane = threadIdx.x & 63;
    const int b = p >> 10;
    const float vy = verts[p*2], vx = verts[p*2 + 1];
    const float cy = (vy + 1.f) * 127.5f;
    const float cx = (vx + 1.f) * 127.5f;
    const float fy = floorf(cy), fx = floorf(cx);
    const int y0 = (int)fy, x0 = (int)fx;
    const float wy = cy - fy, wx = cx - fx;
    float w00 = (1.f - wy) * (1.f - wx), w01 = (1.f - wy) * wx;
    float w10 = wy * (1.f - wx),         w11 = wy * wx;
    const bool vy0 = (unsigned)y0 < 256u, vy1 = (unsigned)(y0 + 1) < 256u;
    const bool vx0 = (unsigned)x0 < 256u, vx1 = (unsigned)(x0 + 1) < 256u;
    w00 = (vy0 && vx0) ? w00 : 0.f;
    w01 = (vy0 && vx1) ? w01 : 0.f;
    w10 = (vy1 && vx0) ? w10 : 0.f;
    w11 = (vy1 && vx1) ? w11 : 0.f;
    const int yc0 = min(max(y0, 0), 255), yc1 = min(max(y0 + 1, 0), 255);
    const int xc0 = min(max(x0, 0), 255), xc1 = min(max(x0 + 1, 0), 255);
    const float* base = fm + (size_t)b * (256 * 256 * 126);
    const float* p00 = base + (yc0 * 256 + xc0) * 126;
    const float* p01 = base + (yc0 * 256 + xc1) * 126;
    const float* p10 = base + (yc1 * 256 + xc0) * 126;
    const float* p11 = base + (yc1 * 256 + xc1) * 126;
    _Float16* xr = X0 + (size_t)p * 128;
    for (int c = lane; c < 126; c += 64) {
        float a = w00 * p00[c] + w01 * p01[c] + w10 * p10[c] + w11 * p11[c];
        xr[c] = (_Float16)a;
    }
    if (lane < 2) xr[126 + lane] = (_Float16)(lane ? vx : vy);
}

// ---- layer-0 GEMM (K=128), m97 structure, 128x128 tile
template<int KTOT>
__global__ __launch_bounds__(256)
void conv_gemm(const _Float16* __restrict__ A, int a_row_stride, int a_batch_stride,
               const _Float16* __restrict__ WT, const float* __restrict__ bias,
               _Float16* __restrict__ Out, int o_row_stride, int o_batch_stride,
               int dil)
{
    __shared__ _Float16 Ald[BM * BK];
    __shared__ _Float16 Bld[BM * BK];
    const int tid  = threadIdx.x;
    const int wid  = tid >> 6;
    const int lane = tid & 63;
    const int b    = blockIdx.x >> 3;
    const int n0   = (blockIdx.x & 7) * BM;
    const int co0  = blockIdx.y * BM;
    const int wm   = wid >> 1, wn = wid & 1;

    const _Float16* Ab = A + (size_t)b * a_batch_stride + (size_t)n0 * a_row_stride;

    f32x4 acc[4][4] = {};

    const int srow = lane >> 3;
    const int scol = (lane & 7) * 8;

    for (int ks = 0; ks < KTOT / BK; ++ks) {
        int ci0, shift;
        if (KTOT == 128) { ci0 = ks * 64; shift = 0; }
        else             { int t = ks >> 3; ci0 = (ks & 7) * 64; shift = (t - 1) * dil; }
        const _Float16* Arow = Ab + (long)shift * a_row_stride + ci0 + scol;
        const _Float16* Brow = WT + (size_t)co0 * KTOT + ks * 64 + scol;
        #pragma unroll
        for (int i = 0; i < 4; ++i) {
            const int r0 = wid * 32 + i * 8;
            load_lds16(Arow + (size_t)(r0 + srow) * a_row_stride, &Ald[r0 * BK]);
            load_lds16(Brow + (size_t)(r0 + srow) * KTOT,         &Bld[r0 * BK]);
        }
        __syncthreads();
        #pragma unroll
        for (int kf = 0; kf < 2; ++kf) {
            f16x8 af[4], bfr[4];
            #pragma unroll
            for (int f = 0; f < 4; ++f) {
                af[f]  = *(const f16x8*)&Ald[(wm*64 + f*16 + (lane & 15)) * BK + kf*32 + (lane >> 4) * 8];
                bfr[f] = *(const f16x8*)&Bld[(wn*64 + f*16 + (lane & 15)) * BK + kf*32 + (lane >> 4) * 8];
            }
            #pragma unroll
            for (int m = 0; m < 4; ++m)
                #pragma unroll
                for (int n = 0; n < 4; ++n)
                    acc[m][n] = __builtin_amdgcn_mfma_f32_16x16x32_f16(af[m], bfr[n], acc[m][n], 0, 0, 0);
        }
        __syncthreads();
    }

    _Float16* Ob = Out + (size_t)b * o_batch_stride + (size_t)n0 * o_row_stride;
    #pragma unroll
    for (int n = 0; n < 4; ++n) {
        const int co = co0 + wn*64 + n*16 + (lane & 15);
        const float bv = bias[co];
        #pragma unroll
        for (int m = 0; m < 4; ++m) {
            #pragma unroll
            for (int j = 0; j < 4; ++j) {
                const int row = wm*64 + m*16 + (lane >> 4)*4 + j;
                float v = acc[m][n][j] + bv;
                v = fmaxf(v, 0.f);
                Ob[(size_t)row * o_row_stride + co] = (_Float16)v;
            }
        }
    }
}

// ---- mid-layer GEMM (r8): r6 geometry (8 waves 4Mx2N, block 256x128, BK=64,
// 3-deep pipeline, 6 gloads/wave/tile, vmcnt(6), T2 swizzle) with ONE barrier
// per tile: [vmcnt|barrier] -> 16 ds_reads -> 6 stages -> 32 MFMA. Cross-wave
// MFMA/LDS overlap at 2 waves/SIMD; compiler emits counted lgkmcnt for reads.
#define NT8 24
__global__ __launch_bounds__(512, 2)
void conv_gemm8(const _Float16* __restrict__ A, const _Float16* __restrict__ WT,
                const float* __restrict__ bias, _Float16* __restrict__ Out, int dil)
{
    extern __shared__ _Float16 smem[];
    _Float16* Ald = smem;                 // [3][256*64]
    _Float16* Bld = smem + 3 * 256 * 64;  // [3][128*64]

    const int tid  = threadIdx.x;
    const int wid  = tid >> 6;
    const int lane = tid & 63;
    const int wm   = wid >> 1;            // 0..3 : 64-row band
    const int wn   = wid & 1;             // 0..1 : 64-col half

    // XCD-aware bijective swizzle (256 blocks, 256%8==0)
    const int orig = blockIdx.x;
    const int swz  = (orig & 7) * 32 + (orig >> 3);
    const int nblk = swz & 3;
    const int mblk = swz >> 2;
    const int b     = mblk >> 2;
    const int n0row = (mblk & 3) * 256;
    const int co0   = nblk * 128;

    const _Float16* Ab = A + (size_t)b * (1056 * 512) + (size_t)n0row * 512;

    // staging: chunk = 64 rows x 64 k (8KB); wave w covers rows 8w..8w+7
    const int srow = lane >> 3;                              // row within wave's 8
    const int scol = (((lane & 7) ^ (lane >> 3)) << 3);      // pre-swizzled global col (f16)

    f32x4 acc[4][4] = {};

    auto stageA = [&](int kt, int c, int ci0, int shift) {
        const int grow = 64 * c + 8 * wid + srow;
        const _Float16* src = Ab + (long)(grow + shift) * 512 + ci0 + scol;
        _Float16* dst = Ald + (kt % 3) * (256 * 64) + (64 * c + 8 * wid) * 64;
        load_lds16(src, dst);
    };
    auto stageB = [&](int kt, int c, int kk) {
        const int grow = 64 * c + 8 * wid + srow;
        const _Float16* src = WT + (size_t)(co0 + grow) * 1536 + kk + scol;
        _Float16* dst = Bld + (kt % 3) * (128 * 64) + (64 * c + 8 * wid) * 64;
        load_lds16(src, dst);
    };
    auto kinfo = [&](int ks, int& ci0, int& shift) {
        const int t = ks >> 3; ci0 = (ks & 7) * 64; shift = (t - 1) * dil;
    };

    // prologue: issue tiles 0 and 1 (6 loads each, fixed order)
    {
        int ci0, sh;
        kinfo(0, ci0, sh);
        stageA(0, 0, ci0, sh); stageA(0, 1, ci0, sh); stageA(0, 2, ci0, sh); stageA(0, 3, ci0, sh);
        stageB(0, 0, 0); stageB(0, 1, 0);
        kinfo(1, ci0, sh);
        stageA(1, 0, ci0, sh); stageA(1, 1, ci0, sh); stageA(1, 2, ci0, sh); stageA(1, 3, ci0, sh);
        stageB(1, 0, 64); stageB(1, 1, 64);
    }

    for (int kt = 0; kt < NT8; ++kt) {
        // pin all prior work (incl. MFMA consuming last tile's frags) before the wait
        __builtin_amdgcn_sched_barrier(0);
        // counted wait: tile kt landed, tile kt+1 (6 loads) stays in flight
        if (kt < NT8 - 1) asm volatile("s_waitcnt vmcnt(6)" ::: "memory");
        else              asm volatile("s_waitcnt vmcnt(0)" ::: "memory");
        __builtin_amdgcn_s_barrier();
        __builtin_amdgcn_sched_barrier(0);

        const _Float16* Abuf = Ald + (kt % 3) * (256 * 64);
        const _Float16* Bbuf = Bld + (kt % 3) * (128 * 64);
        const bool do_stage = (kt + 2 < NT8);
        int nci0 = 0, nsh = 0;
        if (do_stage) kinfo(kt + 2, nci0, nsh);

        // all 16 fragment reads up-front (compiler emits counted lgkmcnt)
        f16x8 bfr[4][2], af[4][2];
        #pragma unroll
        for (int nf = 0; nf < 4; ++nf) {
            const int row = wn * 64 + nf * 16 + (lane & 15);
            #pragma unroll
            for (int kf = 0; kf < 2; ++kf) {
                const int slot = (kf * 4 + (lane >> 4)) ^ (row & 7);
                bfr[nf][kf] = *(const f16x8*)&Bbuf[row * 64 + slot * 8];
            }
        }
        #pragma unroll
        for (int mf = 0; mf < 4; ++mf) {
            const int row = wm * 64 + mf * 16 + (lane & 15);
            #pragma unroll
            for (int kf = 0; kf < 2; ++kf) {
                const int slot = (kf * 4 + (lane >> 4)) ^ (row & 7);
                af[mf][kf] = *(const f16x8*)&Abuf[row * 64 + slot * 8];
            }
        }
        if (do_stage) {
            stageA(kt + 2, 0, nci0, nsh);
            stageA(kt + 2, 1, nci0, nsh);
            stageA(kt + 2, 2, nci0, nsh);
            stageA(kt + 2, 3, nci0, nsh);
            stageB(kt + 2, 0, (kt + 2) * 64);
            stageB(kt + 2, 1, (kt + 2) * 64);
        }
        __builtin_amdgcn_s_setprio(1);
        #pragma unroll
        for (int mf = 0; mf < 4; ++mf)
            #pragma unroll
            for (int nf = 0; nf < 4; ++nf)
                #pragma unroll
                for (int kf = 0; kf < 2; ++kf)
                    acc[mf][nf] = __builtin_amdgcn_mfma_f32_16x16x32_f16(
                        af[mf][kf], bfr[nf][kf], acc[mf][nf], 0, 0, 0);
        __builtin_amdgcn_s_setprio(0);
    }

    _Float16* Ob = Out + (size_t)b * (1056 * 512) + (size_t)n0row * 512;
    #pragma unroll
    for (int nf = 0; nf < 4; ++nf) {
        const int co = co0 + wn * 64 + nf * 16 + (lane & 15);
        const float bv = bias[co];
        #pragma unroll
        for (int m = 0; m < 4; ++m) {
            #pragma unroll
            for (int j = 0; j < 4; ++j) {
                const int row = wm * 64 + m * 16 + (lane >> 4) * 4 + j;
                float v = acc[m][nf][j] + bv;
                v = fmaxf(v, 0.f);
                Ob[(size_t)row * 512 + co] = (_Float16)v;
            }
        }
    }
}

// ---- final 1x1 conv to 2 channels, fp32 out. One wave per row.
__global__ __launch_bounds__(256)
void final_conv(const _Float16* __restrict__ Y, const float* __restrict__ woff,
                float* __restrict__ out)
{
    const int r = blockIdx.x * 4 + (threadIdx.x >> 6);  // 0..16383
    const int lane = threadIdx.x & 63;
    const int b = r >> 10, n = r & 1023;
    const _Float16* yp = Y + ((size_t)b * 1056 + n) * 512 + lane * 8;
    f16x8 yv = *(const f16x8*)yp;
    const int ci0 = lane * 8;
    float s0 = 0.f, s1 = 0.f;
    #pragma unroll
    for (int e = 0; e < 8; ++e) {
        float y = (float)yv[e];
        s0 += y * woff[(ci0 + e) * 2 + 0];
        s1 += y * woff[(ci0 + e) * 2 + 1];
    }
    #pragma unroll
    for (int off = 32; off; off >>= 1) {
        s0 += __shfl_down(s0, off);
        s1 += __shfl_down(s1, off);
    }
    if (lane == 0) { out[r*2] = s0; out[r*2 + 1] = s1; }
}

extern "C" void kernel_launch(void* const* d_in, const int* in_sizes, int n_in,
                              void* d_out, int out_size, void* d_ws, size_t ws_size,
                              hipStream_t stream)
{
    const float* verts = (const float*)d_in[0];
    const float* fm    = (const float*)d_in[1];
    const float* w0    = (const float*)d_in[2];
    const float* b0    = (const float*)d_in[3];
    const float* ws    = (const float*)d_in[4];
    const float* bs    = (const float*)d_in[5];
    const float* woff  = (const float*)d_in[6];
    float* out = (float*)d_out;

    char* wsp = (char*)d_ws;
    _Float16* W0T = (_Float16*)(wsp + OFF_W0T);
    _Float16* WT  = (_Float16*)(wsp + OFF_WT);
    _Float16* X0  = (_Float16*)(wsp + OFF_X0);
    _Float16* Y0  = (_Float16*)(wsp + OFF_Y0);
    _Float16* Y1  = (_Float16*)(wsp + OFF_Y1);
    _Float16* Y0i = Y0 + 16 * 512;   // interior (row 0 of batch 0)
    _Float16* Y1i = Y1 + 16 * 512;

    hipFuncSetAttribute(reinterpret_cast<const void*>(&conv_gemm8),
                        hipFuncAttributeMaxDynamicSharedMemorySize, 147456);

    wprep<<<dim3(8, 8, 19), 256, 0, stream>>>(ws, w0, WT, W0T);
    zeropad<<<1024, 256, 0, stream>>>(Y0, Y1);
    sample_kernel<<<4096, 256, 0, stream>>>(verts, fm, X0);

    // layer 0: 1x1 conv, K=128 (old structure, small K)
    conv_gemm<128><<<dim3(128, 4), 256, 0, stream>>>(
        X0, 128, 1024 * 128, W0T, b0, Y0i, 512, 1056 * 512, 1);

    // 6 dilated mid layers, K=1536, r8 kernel
    const int DIL[6] = {1, 3, 9, 9, 3, 1};
    _Float16* bufs[2] = {Y0i, Y1i};
    for (int l = 0; l < 6; ++l) {
        conv_gemm8<<<256, 512, 147456, stream>>>(
            bufs[l & 1],
            WT + (size_t)l * 512 * 1536, bs + (size_t)l * 512,
            bufs[(l + 1) & 1], DIL[l]);
    }

    // final projection (reads Y0i after 6 layers)
    final_conv<<<4096, 256, 0, stream>>>(bufs[0], woff, out);
}